// Round 15
// baseline (210.355 us; speedup 1.0000x reference)
//
#include <hip/hip_runtime.h>
#include <hip/hip_bf16.h>

// Problem constants
#define DIMV   1024
#define HEADSV 16
#define DHEADV 64
#define WIDTHV 512
#define INNERV 1024
#define BATCHV 2
#define SEQV   4096
#define NROWS  (BATCHV*SEQV)       // 8192
#define KVROWS (WIDTHV + SEQV)     // 4608 = 512 xl prefix + 4096

#define LOG2E 1.4426950408889634f

typedef short bf16x8 __attribute__((ext_vector_type(8)));
typedef short bf16x4 __attribute__((ext_vector_type(4)));
typedef int   int4v  __attribute__((ext_vector_type(4)));
typedef float f32x4  __attribute__((ext_vector_type(4)));

typedef const __attribute__((address_space(1))) void* gvp;
typedef __attribute__((address_space(3))) void* lvp;

static __device__ __forceinline__ short f2bf(float f) {
  __hip_bfloat16 h = __float2bfloat16(f);
  return __builtin_bit_cast(short, h);
}
static __device__ __forceinline__ float bf2f(short s) {
  unsigned u = ((unsigned)(unsigned short)s) << 16;
  return __builtin_bit_cast(float, u);
}
static __device__ __forceinline__ bf16x8 ntload8(const short* p) {
  int4v v = __builtin_nontemporal_load((const int4v*)p);
  return __builtin_bit_cast(bf16x8, v);
}

// ---------------------------------------------------------------- LayerNorm
__global__ __launch_bounds__(256) void ln_kernel(const float* __restrict__ x,
                                                 const float* __restrict__ gamma,
                                                 short* __restrict__ xn) {
  int row = blockIdx.x;                    // 8192 rows
  int t = threadIdx.x;                     // 256 threads, 4 floats each
  const float* xr = x + (size_t)row * DIMV;
  float4 v = reinterpret_cast<const float4*>(xr)[t];
  float s  = v.x + v.y + v.z + v.w;
  float sq = v.x*v.x + v.y*v.y + v.z*v.z + v.w*v.w;
  #pragma unroll
  for (int o = 32; o > 0; o >>= 1) { s += __shfl_down(s, o); sq += __shfl_down(sq, o); }
  __shared__ float red[8];
  int wv = t >> 6;
  if ((t & 63) == 0) { red[wv] = s; red[4 + wv] = sq; }
  __syncthreads();
  s  = red[0] + red[1] + red[2] + red[3];
  sq = red[4] + red[5] + red[6] + red[7];
  float mean = s * (1.0f/1024.0f);
  float var  = sq * (1.0f/1024.0f) - mean*mean;
  float rstd = rsqrtf(var + 1e-5f);
  float4 g = reinterpret_cast<const float4*>(gamma)[t];
  short4 o4;
  o4.x = f2bf((v.x - mean) * rstd * g.x);
  o4.y = f2bf((v.y - mean) * rstd * g.y);
  o4.z = f2bf((v.z - mean) * rstd * g.z);
  o4.w = f2bf((v.w - mean) * rstd * g.w);
  reinterpret_cast<short4*>(xn + (size_t)row * DIMV)[t] = o4;
}

// -------------------------------------- transpose fp32 (R,C) -> bf16 (C,R)
__global__ __launch_bounds__(256) void transpose_f32_bf16(const float* __restrict__ in,
                                                          short* __restrict__ out,
                                                          int R, int C) {
  __shared__ float tile[32][33];
  int tc = blockIdx.x * 32;   // col tile in input
  int tr = blockIdx.y * 32;   // row tile in input
  int tx = threadIdx.x & 31, ty = threadIdx.x >> 5;   // ty 0..7
  #pragma unroll
  for (int i = 0; i < 32; i += 8)
    tile[ty + i][tx] = in[(size_t)(tr + ty + i) * C + tc + tx];
  __syncthreads();
  #pragma unroll
  for (int i = 0; i < 32; i += 8)
    out[(size_t)(tc + ty + i) * R + tr + tx] = f2bf(tile[tx][ty + i]);
}

// ---------------- bias (16,512,1024) fp32 -> fragment-packed bf16 (*log2e)
// bp[h][irow>>2][jcol][r] = bias[h][(irow>>2)*4 + r][jcol] * log2(e)
__global__ __launch_bounds__(256) void pack_bias(const float* __restrict__ in,
                                                 short* __restrict__ out) {
  int idx = blockIdx.x * 256 + threadIdx.x;     // 2,097,152 threads
  int j   = idx & 1023;
  int ir4 = (idx >> 10) & 127;
  int h   = idx >> 17;
  const float* src = in + ((size_t)(h*512 + ir4*4))*1024 + j;
  short4 o;
  o.x = f2bf(src[0]    * LOG2E);
  o.y = f2bf(src[1024] * LOG2E);
  o.z = f2bf(src[2048] * LOG2E);
  o.w = f2bf(src[3072] * LOG2E);
  *reinterpret_cast<short4*>(out + (size_t)idx*4) = o;
}

// --------------------------- xl_memories (2,B,H,512,64) -> k_all / vt heads
// K prefix goes to k_all rows [0,512) (s-major); V prefix goes to vt
// TRANSPOSED (d-major) — transpose_v kernel is deleted, vt is produced
// directly by this kernel (prefix) + gemm_bt<0> epilogue (main rows).
__global__ void xl_to_kv(const float* __restrict__ xl,
                         short* __restrict__ k_all, short* __restrict__ vt) {
  int tid = blockIdx.x * 256 + threadIdx.x;      // 524288 threads, 4 elems each
  int d = (tid & 15) * 4;
  int rest = tid >> 4;
  int s = rest & 511; rest >>= 9;
  int h = rest & 15;  rest >>= 4;
  int b = rest & 1;   int m2 = rest >> 1;
  float4 v = *reinterpret_cast<const float4*>(
      xl + ((((size_t)((m2*2 + b)*16 + h))*512 + s)*64 + d));
  if (m2 == 0) {
    short4 o; o.x = f2bf(v.x); o.y = f2bf(v.y); o.z = f2bf(v.z); o.w = f2bf(v.w);
    *reinterpret_cast<short4*>(
        k_all + (((size_t)(b*16 + h)*KVROWS + s)*64 + d)) = o;
  } else {
    short* base = vt + ((size_t)(b*16 + h)*64 + d)*KVROWS + s;
    base[0*KVROWS] = f2bf(v.x);
    base[1*KVROWS] = f2bf(v.y);
    base[2*KVROWS] = f2bf(v.z);
    base[3*KVROWS] = f2bf(v.w);
  }
}

// ------------------------------------------------------------- MFMA GEMM
// 2-phase pipelined K-loop: BK=64, double-buffered LDS, stage(t+1) issued
// BEFORE compute(t), single __syncthreads per iteration (R9 win: 99->~65us).
// Swizzle involution (both sides, rule 21): LDS slot = src_chunk ^ (row&7).
// MODE 0: N=3072, scatter q(*0.125*log2e)/k_all (bf16), V -> vt TRANSPOSED
//         (d-major; fuses the old transpose_v kernel), + memories (fp32)
// MODE 1: N=1024, plain fp32 output
template<int MODE>
__global__ __launch_bounds__(256) void gemm_bt(
    const short* __restrict__ A, const short* __restrict__ Bm,
    short* __restrict__ qo, short* __restrict__ ko, short* __restrict__ vto,
    float* __restrict__ memo, float* __restrict__ co, int N) {
  __shared__ __align__(16) short As[2][128*64];   // 32 KB
  __shared__ __align__(16) short Bs[2][128*64];   // 32 KB
  const int K = 1024;
  int bm = blockIdx.x * 128;
  int bn = blockIdx.y * 128;
  int tid = threadIdx.x;
  int lane = tid & 63, wid = tid >> 6;
  int wr = wid >> 1, wc = wid & 1;
  int fr = lane & 15, fq = lane >> 4;

  // staging geometry: 1024 chunk-slots (128 rows x 8 chunks of 16B) per matrix,
  // 256 threads x 4 passes; pass p covers rows p*32..p*32+31.
  const int r0 = tid >> 3;                 // row within pass (0..31)
  const int sl = tid & 7;                  // dest slot
  const int sc = sl ^ (r0 & 7);            // source chunk ((p*32+r0)&7 == r0&7)
  const short* agp = A  + (size_t)(bm + r0)*K + sc*8;
  const short* bgp = Bm + (size_t)(bn + r0)*K + sc*8;
  const int wbase = wid*64*8;              // wave-uniform LDS base (shorts), p adds 256*8

  f32x4 acc[4][4] = {};

  auto stage = [&](int bufi, int k0) {
    #pragma unroll
    for (int p = 0; p < 4; ++p) {
      __builtin_amdgcn_global_load_lds(
          (gvp)(const void*)(agp + (size_t)p*32*K + k0),
          (lvp)(void*)(&As[bufi][p*2048 + wbase]), 16, 0, 0);
      __builtin_amdgcn_global_load_lds(
          (gvp)(const void*)(bgp + (size_t)p*32*K + k0),
          (lvp)(void*)(&Bs[bufi][p*2048 + wbase]), 16, 0, 0);
    }
  };

  stage(0, 0);
  __syncthreads();

  for (int it = 0; it < 16; ++it) {
    const int buf = it & 1;
    if (it < 15) stage(buf ^ 1, (it + 1) * 64);
    __builtin_amdgcn_sched_barrier(0);     // pin prefetch issue before compute
    #pragma unroll
    for (int kc = 0; kc < 2; ++kc) {
      const int ca = kc*4 + fq;            // desired source chunk
      bf16x8 af[4], bfr[4];
      #pragma unroll
      for (int i = 0; i < 4; ++i) {
        int ra = wr*64 + i*16 + fr;
        int rb = wc*64 + i*16 + fr;
        af[i]  = *reinterpret_cast<const bf16x8*>(&As[buf][ra*64 + (ca ^ (ra & 7))*8]);
        bfr[i] = *reinterpret_cast<const bf16x8*>(&Bs[buf][rb*64 + (ca ^ (rb & 7))*8]);
      }
      #pragma unroll
      for (int i = 0; i < 4; ++i)
        #pragma unroll
        for (int j = 0; j < 4; ++j)
          acc[i][j] = __builtin_amdgcn_mfma_f32_16x16x32_bf16(af[i], bfr[j], acc[i][j], 0, 0, 0);
    }
    __syncthreads();                       // drains vmcnt for buf^1 + protects buf reuse
  }

  if (MODE == 0) {
    #pragma unroll
    for (int i = 0; i < 4; ++i)
      #pragma unroll
      for (int j = 0; j < 4; ++j)
        #pragma unroll
        for (int r = 0; r < 4; ++r) {
          int m = bm + wr*64 + i*16 + fq*4 + r;
          int n = bn + wc*64 + j*16 + fr;
          float val = acc[i][j][r];
          int b = m >> 12, s = m & 4095;
          if (n < 1024) {
            qo[(size_t)m*1024 + n] = f2bf(val * (0.125f * LOG2E));  // fold scale+log2e
          } else {
            int h = (n >> 6) & 15, d = n & 63;
            if (n < 2048) {
              ko[((size_t)((b << 4) + h)*KVROWS + 512 + s)*64 + d] = f2bf(val);
            } else {
              // V -> vt transposed (d-major): fused transpose_v
              vto[(((size_t)((b << 4) + h))*64 + d)*KVROWS + 512 + s] = f2bf(val);
            }
            if (s >= 3584) {   // last window -> memories output, fp32
              int m2 = (n < 2048) ? 0 : 1;
              memo[((size_t)(((m2*2 + b) << 4) + h)*512 + (s - 3584))*64 + d] = val;
            }
          }
        }
  } else {
    #pragma unroll
    for (int i = 0; i < 4; ++i)
      #pragma unroll
      for (int j = 0; j < 4; ++j)
        #pragma unroll
        for (int r = 0; r < 4; ++r) {
          int m = bm + wr*64 + i*16 + fq*4 + r;
          int n = bn + wc*64 + j*16 + fr;
          co[(size_t)m*N + n] = acc[i][j][r];
        }
  }
}

// ------------------------------------------------------- flash attention
// R10 structure (proven 85us local optimum after the R11-R13 ablation arc):
// K LDS-staged cooperatively + reg-prefetch + 2 block barriers per tile;
// V/bias direct from L2; per-wave P in LDS. 4 waves x 32 q-rows, grid 1024.
// R11 (K direct, no barriers): 122us — K is consumed immediately, L2 latency
//   lands on the critical path.
// R12 (16-row waves): 125us — per-wave K/V overhead amortization dominates.
// R13 (K reg-dbuf): 120us — allocator sinks the prefetch (VGPR pressure).
// Fixed-max softmax (exp2 direct, log2e pre-folded into q and bias).
// __launch_bounds__(256, 2): live set ~100 VGPRs; (256,3) forced spills.
__global__ __launch_bounds__(256, 2) void attn_kernel(
    const short* __restrict__ q,      // (8192, 1024), pre-scaled 0.125*log2e
    const short* __restrict__ k_all,  // (32, 4608, 64)
    const short* __restrict__ vt,     // (32, 64, 4608)
    const short* __restrict__ bp,     // (16,128,1024,4) packed bf16 *log2e
    short* __restrict__ attnb) {      // (8192, 1024)
  __shared__ __align__(16) short Ks[2][64*72];
  __shared__ __align__(16) short Pb[4][16*72];   // per-wave, single-buffered

  const int bid = blockIdx.x;
  // grid bits: h[0:4) | w[4:7) | b[7] | cq[8:10)
  const int h = bid & 15, w = (bid >> 4) & 7, b = (bid >> 7) & 1;
  const int cq = 3 - (bid >> 8);
  const int tid = threadIdx.x, lane = tid & 63, wid = tid >> 6;
  const int fr = lane & 15, fq = lane >> 4;
  const int qoff = cq*128 + wid*32;              // window-local q start

  // Q fragments in registers (read-once -> nontemporal, protects L2 for K/V)
  const short* qrow = q + ((size_t)(b*SEQV + w*WIDTHV + qoff))*1024 + h*64;
  bf16x8 qf[2][2];
  #pragma unroll
  for (int i = 0; i < 2; ++i)
    #pragma unroll
    for (int c = 0; c < 2; ++c)
      qf[i][c] = ntload8(qrow + (size_t)(i*16 + fr)*1024 + c*32 + fq*8);

  f32x4 o[2][4] = {};
  float racc[2][4] = {{0.f,0.f,0.f,0.f},{0.f,0.f,0.f,0.f}};

  const short* kg  = k_all + ((size_t)(b*16 + h)*KVROWS + w*512)*64;
  const short* vg  = vt    + (size_t)(b*16 + h)*64*KVROWS + w*512;
  const short* bpw = bp    + ((size_t)(h*128 + (qoff >> 2) + fq))*4096;

  // K staging coords: 256 threads x 2 passes x 16B = one 64x64 bf16 tile
  const int sr = tid >> 3, sc = tid & 7;
  const short* kgs = kg + (size_t)sr*64 + sc*8;
  const int soA = sr*72 + sc*8;                  // pass p adds 32*72

  { // prologue: stage K tile 0 into buf 0
    int4v k0v[2];
    #pragma unroll
    for (int p = 0; p < 2; ++p)
      k0v[p] = *reinterpret_cast<const int4v*>(kgs + p*32*64);
    #pragma unroll
    for (int p = 0; p < 2; ++p)
      *reinterpret_cast<int4v*>(&Ks[0][soA + p*2304]) = k0v[p];
  }
  __syncthreads();

  const int NT = 2*cq + 10;                       // tiles this block stages
  const int tmaxw = 2*cq + 8 + (wid >> 1);        // wave's diagonal tile

  for (int t = 0; t < NT; ++t) {
    const int buf = t & 1;
    int4v kk[2];
    const bool more = (t + 1 < NT);
    if (more) {
      #pragma unroll
      for (int p = 0; p < 2; ++p)
        kk[p] = *reinterpret_cast<const int4v*>(kgs + (size_t)(t+1)*4096 + p*32*64);
    }
    if (t <= tmaxw) {
      const int j0 = t * 64;
      // bias fragments (coalesced 8B loads, L2-resident slice)
      bf16x4 bb[2][4];
      #pragma unroll
      for (int i = 0; i < 2; ++i)
        #pragma unroll
        for (int jc = 0; jc < 4; ++jc)
          bb[i][jc] = *reinterpret_cast<const bf16x4*>(
              &bpw[(size_t)i*16384 + (size_t)(j0 + jc*16 + fr)*4]);
      bf16x8 kf0[4], kf1[4];
      #pragma unroll
      for (int jc = 0; jc < 4; ++jc) {
        kf0[jc] = *reinterpret_cast<const bf16x8*>(&Ks[buf][(jc*16 + fr)*72 + fq*8]);
        kf1[jc] = *reinterpret_cast<const bf16x8*>(&Ks[buf][(jc*16 + fr)*72 + 32 + fq*8]);
      }
      // V fragments direct from global (L2-resident vt slice); issued early so
      // QK^T + softmax hides the L2 latency before PV consumes them.
      bf16x8 vf[2][4];
      #pragma unroll
      for (int jk = 0; jk < 2; ++jk)
        #pragma unroll
        for (int dc = 0; dc < 4; ++dc)
          vf[jk][dc] = *reinterpret_cast<const bf16x8*>(
              vg + (size_t)(dc*16 + fr)*KVROWS + j0 + jk*32 + fq*8);

      // QK^T (log2-domain) with bias as C-init
      f32x4 s[2][4];
      __builtin_amdgcn_s_setprio(1);
      #pragma unroll
      for (int i = 0; i < 2; ++i)
        #pragma unroll
        for (int jc = 0; jc < 4; ++jc) {
          f32x4 c;
          c[0] = bf2f(bb[i][jc][0]); c[1] = bf2f(bb[i][jc][1]);
          c[2] = bf2f(bb[i][jc][2]); c[3] = bf2f(bb[i][jc][3]);
          s[i][jc] = __builtin_amdgcn_mfma_f32_16x16x32_bf16(qf[i][0], kf0[jc], c, 0, 0, 0);
        }
      #pragma unroll
      for (int i = 0; i < 2; ++i)
        #pragma unroll
        for (int jc = 0; jc < 4; ++jc)
          s[i][jc] = __builtin_amdgcn_mfma_f32_16x16x32_bf16(qf[i][1], kf1[jc], s[i][jc], 0, 0, 0);
      __builtin_amdgcn_s_setprio(0);

      if (t == tmaxw) {   // only the diagonal tile needs causal masking
        #pragma unroll
        for (int i = 0; i < 2; ++i)
          #pragma unroll
          for (int jc = 0; jc < 4; ++jc)
            #pragma unroll
            for (int r = 0; r < 4; ++r)
              if (j0 + jc*16 + fr > qoff + i*16 + fq*4 + r + 512)
                s[i][jc][r] = -1e30f;
      }

      #pragma unroll
      for (int i = 0; i < 2; ++i) {
        short* Pw = &Pb[wid][0];
        #pragma unroll
        for (int jc = 0; jc < 4; ++jc)
          #pragma unroll
          for (int r = 0; r < 4; ++r) {
            float p = exp2f(fminf(s[i][jc][r], 80.f));
            racc[i][r] += p;
            Pw[(fq*4 + r)*72 + jc*16 + fr] = f2bf(p);
          }
        asm volatile("s_waitcnt lgkmcnt(0)" ::: "memory");  // P visible cross-lane
        __builtin_amdgcn_sched_barrier(0);   // rule 18: pin reads after the wait
        __builtin_amdgcn_s_setprio(1);
        #pragma unroll
        for (int jk = 0; jk < 2; ++jk) {
          bf16x8 pf = *reinterpret_cast<const bf16x8*>(&Pw[fr*72 + jk*32 + fq*8]);
          #pragma unroll
          for (int dc = 0; dc < 4; ++dc)
            o[i][dc] = __builtin_amdgcn_mfma_f32_16x16x32_bf16(pf, vf[jk][dc], o[i][dc], 0, 0, 0);
        }
        __builtin_amdgcn_s_setprio(0);
        __builtin_amdgcn_sched_barrier(0);   // pin next-i P writes after these reads
      }
    }
    if (more) {   // write next K tile into the other buffer
      #pragma unroll
      for (int p = 0; p < 2; ++p)
        *reinterpret_cast<int4v*>(&Ks[buf ^ 1][soA + p*2304]) = kk[p];
    }
    __syncthreads();
  }

  // single end-of-kernel sum reduction across the 16 fr lanes
  #pragma unroll
  for (int i = 0; i < 2; ++i)
    #pragma unroll
    for (int off = 1; off < 16; off <<= 1)
      #pragma unroll
      for (int r = 0; r < 4; ++r)
        racc[i][r] += __shfl_xor(racc[i][r], off);

  short* obase = attnb + ((size_t)(b*SEQV + w*WIDTHV + qoff))*1024 + h*64;
  #pragma unroll
  for (int i = 0; i < 2; ++i) {
    float inv[4];
    #pragma unroll
    for (int r = 0; r < 4; ++r) inv[r] = 1.0f / racc[i][r];
    #pragma unroll
    for (int dc = 0; dc < 4; ++dc)
      #pragma unroll
      for (int r = 0; r < 4; ++r)
        obase[(size_t)(i*16 + fq*4 + r)*1024 + dc*16 + fr] = f2bf(o[i][dc][r] * inv[r]);
  }
}

// ------------------------------------------------------------------- host
extern "C" void kernel_launch(void* const* d_in, const int* in_sizes, int n_in,
                              void* d_out, int out_size, void* d_ws, size_t ws_size,
                              hipStream_t stream) {
  const float* x     = (const float*)d_in[0];
  const float* bias  = (const float*)d_in[1];
  const float* xl    = (const float*)d_in[2];
  const float* gamma = (const float*)d_in[3];
  const float* w_qkv = (const float*)d_in[4];
  const float* w_out = (const float*)d_in[5];
  float* out = (float*)d_out;
  float* mem_out = out + (size_t)BATCHV*SEQV*DIMV;   // +8388608

  char* ws = (char*)d_ws;
  size_t off = 0;
  auto alloc = [&](size_t bytes) { size_t o = off; off += (bytes + 255) & ~(size_t)255; return o; };
  short* xn    = (short*)(ws + alloc((size_t)NROWS*DIMV*2));          // aliased by attnb
  short* wqkvT = (short*)(ws + alloc((size_t)3*INNERV*DIMV*2));
  short* woutT = (short*)(ws + alloc((size_t)DIMV*INNERV*2));
  short* bp    = (short*)(ws + alloc((size_t)HEADSV*128*1024*4*2));   // packed bias
  short* qbuf  = (short*)(ws + alloc((size_t)NROWS*INNERV*2));
  short* k_all = (short*)(ws + alloc((size_t)BATCHV*HEADSV*KVROWS*DHEADV*2));
  short* vt    = (short*)(ws + alloc((size_t)BATCHV*HEADSV*KVROWS*DHEADV*2));
  short* attnb = xn;  // xn dead after QKV GEMM; reuse for attention output

  // weight transposes (fp32 (R,C) -> bf16 (C,R))
  transpose_f32_bf16<<<dim3(3*INNERV/32, DIMV/32), 256, 0, stream>>>(w_qkv, wqkvT, DIMV, 3*INNERV);
  transpose_f32_bf16<<<dim3(INNERV/32, DIMV/32), 256, 0, stream>>>(w_out, woutT, DIMV, INNERV);
  // bias -> fragment-packed bf16 (*log2e)
  pack_bias<<<8192, 256, 0, stream>>>(bias, bp);
  // xl memories -> k_all prefix (s-major) + vt prefix (d-major, transposed)
  xl_to_kv<<<2048, 256, 0, stream>>>(xl, k_all, vt);
  // layernorm
  ln_kernel<<<NROWS, 256, 0, stream>>>(x, gamma, xn);
  // QKV projection (q pre-scaled; K s-major; V written TRANSPOSED into vt;
  // memories fp32 epilogue) — transpose_v kernel deleted.
  gemm_bt<0><<<dim3(NROWS/128, (3*INNERV)/128), 256, 0, stream>>>(
      xn, wqkvT, qbuf, k_all, vt, mem_out, nullptr, 3*INNERV);
  // attention: 1024 blocks (heavy-first), 4 waves x 32 q-rows (R10 structure)
  attn_kernel<<<4*BATCHV*8*HEADSV, 256, 0, stream>>>(qbuf, k_all, vt, bp, attnb);
  // output projection -> fp32 d_out
  gemm_bt<1><<<dim3(NROWS/128, INNERV/128), 256, 0, stream>>>(
      attnb, woutT, nullptr, nullptr, nullptr, nullptr, out, INNERV);
}

// Round 16
// 201.773 us; speedup vs baseline: 1.0425x; 1.0425x over previous
//
#include <hip/hip_runtime.h>
#include <hip/hip_bf16.h>

// Problem constants
#define DIMV   1024
#define HEADSV 16
#define DHEADV 64
#define WIDTHV 512
#define INNERV 1024
#define BATCHV 2
#define SEQV   4096
#define NROWS  (BATCHV*SEQV)       // 8192
#define KVROWS (WIDTHV + SEQV)     // 4608 = 512 xl prefix + 4096

#define LOG2E 1.4426950408889634f

typedef short bf16x8 __attribute__((ext_vector_type(8)));
typedef short bf16x4 __attribute__((ext_vector_type(4)));
typedef int   int4v  __attribute__((ext_vector_type(4)));
typedef float f32x4  __attribute__((ext_vector_type(4)));

typedef const __attribute__((address_space(1))) void* gvp;
typedef __attribute__((address_space(3))) void* lvp;

static __device__ __forceinline__ short f2bf(float f) {
  __hip_bfloat16 h = __float2bfloat16(f);
  return __builtin_bit_cast(short, h);
}
static __device__ __forceinline__ float bf2f(short s) {
  unsigned u = ((unsigned)(unsigned short)s) << 16;
  return __builtin_bit_cast(float, u);
}
static __device__ __forceinline__ bf16x8 ntload8(const short* p) {
  int4v v = __builtin_nontemporal_load((const int4v*)p);
  return __builtin_bit_cast(bf16x8, v);
}

// ---------------------------------------------------------------- LayerNorm
__global__ __launch_bounds__(256) void ln_kernel(const float* __restrict__ x,
                                                 const float* __restrict__ gamma,
                                                 short* __restrict__ xn) {
  int row = blockIdx.x;                    // 8192 rows
  int t = threadIdx.x;                     // 256 threads, 4 floats each
  const float* xr = x + (size_t)row * DIMV;
  float4 v = reinterpret_cast<const float4*>(xr)[t];
  float s  = v.x + v.y + v.z + v.w;
  float sq = v.x*v.x + v.y*v.y + v.z*v.z + v.w*v.w;
  #pragma unroll
  for (int o = 32; o > 0; o >>= 1) { s += __shfl_down(s, o); sq += __shfl_down(sq, o); }
  __shared__ float red[8];
  int wv = t >> 6;
  if ((t & 63) == 0) { red[wv] = s; red[4 + wv] = sq; }
  __syncthreads();
  s  = red[0] + red[1] + red[2] + red[3];
  sq = red[4] + red[5] + red[6] + red[7];
  float mean = s * (1.0f/1024.0f);
  float var  = sq * (1.0f/1024.0f) - mean*mean;
  float rstd = rsqrtf(var + 1e-5f);
  float4 g = reinterpret_cast<const float4*>(gamma)[t];
  short4 o4;
  o4.x = f2bf((v.x - mean) * rstd * g.x);
  o4.y = f2bf((v.y - mean) * rstd * g.y);
  o4.z = f2bf((v.z - mean) * rstd * g.z);
  o4.w = f2bf((v.w - mean) * rstd * g.w);
  reinterpret_cast<short4*>(xn + (size_t)row * DIMV)[t] = o4;
}

// -------------------------------------- transpose fp32 (R,C) -> bf16 (C,R)
__global__ __launch_bounds__(256) void transpose_f32_bf16(const float* __restrict__ in,
                                                          short* __restrict__ out,
                                                          int R, int C) {
  __shared__ float tile[32][33];
  int tc = blockIdx.x * 32;   // col tile in input
  int tr = blockIdx.y * 32;   // row tile in input
  int tx = threadIdx.x & 31, ty = threadIdx.x >> 5;   // ty 0..7
  #pragma unroll
  for (int i = 0; i < 32; i += 8)
    tile[ty + i][tx] = in[(size_t)(tr + ty + i) * C + tc + tx];
  __syncthreads();
  #pragma unroll
  for (int i = 0; i < 32; i += 8)
    out[(size_t)(tc + ty + i) * R + tr + tx] = f2bf(tile[tx][ty + i]);
}

// ---------------- bias (16,512,1024) fp32 -> fragment-packed bf16 (*log2e)
// bp[h][irow>>2][jcol][r] = bias[h][(irow>>2)*4 + r][jcol] * log2(e)
__global__ __launch_bounds__(256) void pack_bias(const float* __restrict__ in,
                                                 short* __restrict__ out) {
  int idx = blockIdx.x * 256 + threadIdx.x;     // 2,097,152 threads
  int j   = idx & 1023;
  int ir4 = (idx >> 10) & 127;
  int h   = idx >> 17;
  const float* src = in + ((size_t)(h*512 + ir4*4))*1024 + j;
  short4 o;
  o.x = f2bf(src[0]    * LOG2E);
  o.y = f2bf(src[1024] * LOG2E);
  o.z = f2bf(src[2048] * LOG2E);
  o.w = f2bf(src[3072] * LOG2E);
  *reinterpret_cast<short4*>(out + (size_t)idx*4) = o;
}

// --------------------------- xl_memories (2,B,H,512,64) -> k_all / vt heads
// K prefix -> k_all rows [0,512) (s-major); V prefix -> vt TRANSPOSED
// (d-major). transpose_v kernel is deleted; vt is produced here (prefix) +
// gemm_bt<0> epilogue (main rows).
__global__ void xl_to_kv(const float* __restrict__ xl,
                         short* __restrict__ k_all, short* __restrict__ vt) {
  int tid = blockIdx.x * 256 + threadIdx.x;      // 524288 threads, 4 elems each
  int d = (tid & 15) * 4;
  int rest = tid >> 4;
  int s = rest & 511; rest >>= 9;
  int h = rest & 15;  rest >>= 4;
  int b = rest & 1;   int m2 = rest >> 1;
  float4 v = *reinterpret_cast<const float4*>(
      xl + ((((size_t)((m2*2 + b)*16 + h))*512 + s)*64 + d));
  if (m2 == 0) {
    short4 o; o.x = f2bf(v.x); o.y = f2bf(v.y); o.z = f2bf(v.z); o.w = f2bf(v.w);
    *reinterpret_cast<short4*>(
        k_all + (((size_t)(b*16 + h)*KVROWS + s)*64 + d)) = o;
  } else {
    short* base = vt + ((size_t)(b*16 + h)*64 + d)*KVROWS + s;
    base[0*KVROWS] = f2bf(v.x);
    base[1*KVROWS] = f2bf(v.y);
    base[2*KVROWS] = f2bf(v.z);
    base[3*KVROWS] = f2bf(v.w);
  }
}

// ------------------------------------------------------------- MFMA GEMM
// 2-phase pipelined K-loop (R9 win). Swizzle involution: slot = chunk^(row&7).
// MODE 0: N=3072. Block-clean n-split: blockIdx.y<8 = Q (scaled), 8..15 = K
//   (s-major), 16..23 = V — V is transposed to d-major via an LDS-staged
//   epilogue (R15 fix: the direct scatter was 64 scalar 2B stores/thread,
//   ~64 lines/instruction; now 8x dwordx4 via LDS T[n][m]).
// MODE 1: N=1024, plain fp32 output.
template<int MODE>
__global__ __launch_bounds__(256) void gemm_bt(
    const short* __restrict__ A, const short* __restrict__ Bm,
    short* __restrict__ qo, short* __restrict__ ko, short* __restrict__ vto,
    float* __restrict__ memo, float* __restrict__ co, int N) {
  __shared__ __align__(16) short LDS[4][128*64];   // [0..1]=A dbuf, [2..3]=B dbuf; 64 KB
  const int K = 1024;
  int bm = blockIdx.x * 128;
  int bn = blockIdx.y * 128;
  int tid = threadIdx.x;
  int lane = tid & 63, wid = tid >> 6;
  int wr = wid >> 1, wc = wid & 1;
  int fr = lane & 15, fq = lane >> 4;

  // staging geometry: 1024 chunk-slots (128 rows x 8 chunks of 16B) per matrix,
  // 256 threads x 4 passes; pass p covers rows p*32..p*32+31.
  const int r0 = tid >> 3;                 // row within pass (0..31)
  const int sl = tid & 7;                  // dest slot
  const int sc = sl ^ (r0 & 7);            // source chunk ((p*32+r0)&7 == r0&7)
  const short* agp = A  + (size_t)(bm + r0)*K + sc*8;
  const short* bgp = Bm + (size_t)(bn + r0)*K + sc*8;
  const int wbase = wid*64*8;              // wave-uniform LDS base (shorts), p adds 256*8

  f32x4 acc[4][4] = {};

  auto stage = [&](int bufi, int k0) {
    #pragma unroll
    for (int p = 0; p < 4; ++p) {
      __builtin_amdgcn_global_load_lds(
          (gvp)(const void*)(agp + (size_t)p*32*K + k0),
          (lvp)(void*)(&LDS[bufi][p*2048 + wbase]), 16, 0, 0);
      __builtin_amdgcn_global_load_lds(
          (gvp)(const void*)(bgp + (size_t)p*32*K + k0),
          (lvp)(void*)(&LDS[2 + bufi][p*2048 + wbase]), 16, 0, 0);
    }
  };

  stage(0, 0);
  __syncthreads();

  for (int it = 0; it < 16; ++it) {
    const int buf = it & 1;
    if (it < 15) stage(buf ^ 1, (it + 1) * 64);
    __builtin_amdgcn_sched_barrier(0);     // pin prefetch issue before compute
    #pragma unroll
    for (int kc = 0; kc < 2; ++kc) {
      const int ca = kc*4 + fq;            // desired source chunk
      bf16x8 af[4], bfr[4];
      #pragma unroll
      for (int i = 0; i < 4; ++i) {
        int ra = wr*64 + i*16 + fr;
        int rb = wc*64 + i*16 + fr;
        af[i]  = *reinterpret_cast<const bf16x8*>(&LDS[buf][ra*64 + (ca ^ (ra & 7))*8]);
        bfr[i] = *reinterpret_cast<const bf16x8*>(&LDS[2 + buf][rb*64 + (ca ^ (rb & 7))*8]);
      }
      #pragma unroll
      for (int i = 0; i < 4; ++i)
        #pragma unroll
        for (int j = 0; j < 4; ++j)
          acc[i][j] = __builtin_amdgcn_mfma_f32_16x16x32_bf16(af[i], bfr[j], acc[i][j], 0, 0, 0);
    }
    __syncthreads();                       // drains vmcnt for buf^1 + protects buf reuse
  }

  if (MODE == 0) {
    if (bn < 2048) {
      // ---- Q / K blocks: direct coalesced-ish scalar epilogue (unchanged)
      #pragma unroll
      for (int i = 0; i < 4; ++i)
        #pragma unroll
        for (int j = 0; j < 4; ++j)
          #pragma unroll
          for (int r = 0; r < 4; ++r) {
            int m = bm + wr*64 + i*16 + fq*4 + r;
            int n = bn + wc*64 + j*16 + fr;
            float val = acc[i][j][r];
            int b = m >> 12, s = m & 4095;
            if (n < 1024) {
              qo[(size_t)m*1024 + n] = f2bf(val * (0.125f * LOG2E));  // fold scale+log2e
            } else {
              int h = (n >> 6) & 15, d = n & 63;
              ko[((size_t)((b << 4) + h)*KVROWS + 512 + s)*64 + d] = f2bf(val);
              if (s >= 3584)   // last window -> K memories (m2=0), fp32
                memo[((size_t)((b << 4) + h)*512 + (s - 3584))*64 + d] = val;
            }
          }
    } else {
      // ---- V blocks: LDS-staged transpose to d-major vt (+ V memories)
      short* T = &LDS[0][0];               // 128 x stride-136 shorts = 34 KB
      #pragma unroll
      for (int i = 0; i < 4; ++i)
        #pragma unroll
        for (int j = 0; j < 4; ++j)
          #pragma unroll
          for (int r = 0; r < 4; ++r) {
            int ml = wr*64 + i*16 + fq*4 + r;
            int nl = wc*64 + j*16 + fr;
            float val = acc[i][j][r];
            T[nl*136 + ml] = f2bf(val);
            int m = bm + ml, s = m & 4095;
            if (s >= 3584) {               // V memories (m2=1), fp32
              int b = m >> 12, n = bn + nl;
              int h = (n >> 6) & 15, d = n & 63;
              memo[((size_t)(((2 + b) << 4) + h)*512 + (s - 3584))*64 + d] = val;
            }
          }
      __syncthreads();
      const int nl = tid >> 1, half = tid & 1;
      const int n = bn + nl;
      const int h = (n >> 6) & 15, d = n & 63;
      const int b = bm >> 12, s0 = bm & 4095;
      short* dst = vto + ((size_t)((b << 4) + h)*64 + d)*KVROWS + 512 + s0 + half*64;
      const short* src = &T[nl*136 + half*64];
      #pragma unroll
      for (int c = 0; c < 8; ++c)
        *reinterpret_cast<int4v*>(dst + c*8) =
            *reinterpret_cast<const int4v*>(src + c*8);
    }
  } else {
    #pragma unroll
    for (int i = 0; i < 4; ++i)
      #pragma unroll
      for (int j = 0; j < 4; ++j)
        #pragma unroll
        for (int r = 0; r < 4; ++r) {
          int m = bm + wr*64 + i*16 + fq*4 + r;
          int n = bn + wc*64 + j*16 + fr;
          co[(size_t)m*N + n] = acc[i][j][r];
        }
  }
}

// ------------------------------------------------------- flash attention
// R10 structure (proven 85us local optimum after the R11-R13 ablation arc):
// K LDS-staged cooperatively + reg-prefetch + 2 block barriers per tile;
// V/bias direct from L2; per-wave P in LDS. 4 waves x 32 q-rows, grid 1024.
// Fixed-max softmax (exp2 direct, log2e pre-folded into q and bias).
// __launch_bounds__(256, 2): live set ~100 VGPRs; (256,3) forced spills.
__global__ __launch_bounds__(256, 2) void attn_kernel(
    const short* __restrict__ q,      // (8192, 1024), pre-scaled 0.125*log2e
    const short* __restrict__ k_all,  // (32, 4608, 64)
    const short* __restrict__ vt,     // (32, 64, 4608)
    const short* __restrict__ bp,     // (16,128,1024,4) packed bf16 *log2e
    short* __restrict__ attnb) {      // (8192, 1024)
  __shared__ __align__(16) short Ks[2][64*72];
  __shared__ __align__(16) short Pb[4][16*72];   // per-wave, single-buffered

  const int bid = blockIdx.x;
  // grid bits: h[0:4) | w[4:7) | b[7] | cq[8:10)
  const int h = bid & 15, w = (bid >> 4) & 7, b = (bid >> 7) & 1;
  const int cq = 3 - (bid >> 8);
  const int tid = threadIdx.x, lane = tid & 63, wid = tid >> 6;
  const int fr = lane & 15, fq = lane >> 4;
  const int qoff = cq*128 + wid*32;              // window-local q start

  // Q fragments in registers (read-once -> nontemporal, protects L2 for K/V)
  const short* qrow = q + ((size_t)(b*SEQV + w*WIDTHV + qoff))*1024 + h*64;
  bf16x8 qf[2][2];
  #pragma unroll
  for (int i = 0; i < 2; ++i)
    #pragma unroll
    for (int c = 0; c < 2; ++c)
      qf[i][c] = ntload8(qrow + (size_t)(i*16 + fr)*1024 + c*32 + fq*8);

  f32x4 o[2][4] = {};
  float racc[2][4] = {{0.f,0.f,0.f,0.f},{0.f,0.f,0.f,0.f}};

  const short* kg  = k_all + ((size_t)(b*16 + h)*KVROWS + w*512)*64;
  const short* vg  = vt    + (size_t)(b*16 + h)*64*KVROWS + w*512;
  const short* bpw = bp    + ((size_t)(h*128 + (qoff >> 2) + fq))*4096;

  // K staging coords: 256 threads x 2 passes x 16B = one 64x64 bf16 tile
  const int sr = tid >> 3, sc = tid & 7;
  const short* kgs = kg + (size_t)sr*64 + sc*8;
  const int soA = sr*72 + sc*8;                  // pass p adds 32*72

  { // prologue: stage K tile 0 into buf 0
    int4v k0v[2];
    #pragma unroll
    for (int p = 0; p < 2; ++p)
      k0v[p] = *reinterpret_cast<const int4v*>(kgs + p*32*64);
    #pragma unroll
    for (int p = 0; p < 2; ++p)
      *reinterpret_cast<int4v*>(&Ks[0][soA + p*2304]) = k0v[p];
  }
  __syncthreads();

  const int NT = 2*cq + 10;                       // tiles this block stages
  const int tmaxw = 2*cq + 8 + (wid >> 1);        // wave's diagonal tile

  for (int t = 0; t < NT; ++t) {
    const int buf = t & 1;
    int4v kk[2];
    const bool more = (t + 1 < NT);
    if (more) {
      #pragma unroll
      for (int p = 0; p < 2; ++p)
        kk[p] = *reinterpret_cast<const int4v*>(kgs + (size_t)(t+1)*4096 + p*32*64);
    }
    if (t <= tmaxw) {
      const int j0 = t * 64;
      // bias fragments (coalesced 8B loads, L2-resident slice)
      bf16x4 bb[2][4];
      #pragma unroll
      for (int i = 0; i < 2; ++i)
        #pragma unroll
        for (int jc = 0; jc < 4; ++jc)
          bb[i][jc] = *reinterpret_cast<const bf16x4*>(
              &bpw[(size_t)i*16384 + (size_t)(j0 + jc*16 + fr)*4]);
      bf16x8 kf0[4], kf1[4];
      #pragma unroll
      for (int jc = 0; jc < 4; ++jc) {
        kf0[jc] = *reinterpret_cast<const bf16x8*>(&Ks[buf][(jc*16 + fr)*72 + fq*8]);
        kf1[jc] = *reinterpret_cast<const bf16x8*>(&Ks[buf][(jc*16 + fr)*72 + 32 + fq*8]);
      }
      // V fragments direct from global (L2-resident vt slice); issued early so
      // QK^T + softmax hides the L2 latency before PV consumes them.
      bf16x8 vf[2][4];
      #pragma unroll
      for (int jk = 0; jk < 2; ++jk)
        #pragma unroll
        for (int dc = 0; dc < 4; ++dc)
          vf[jk][dc] = *reinterpret_cast<const bf16x8*>(
              vg + (size_t)(dc*16 + fr)*KVROWS + j0 + jk*32 + fq*8);

      // QK^T (log2-domain) with bias as C-init
      f32x4 s[2][4];
      __builtin_amdgcn_s_setprio(1);
      #pragma unroll
      for (int i = 0; i < 2; ++i)
        #pragma unroll
        for (int jc = 0; jc < 4; ++jc) {
          f32x4 c;
          c[0] = bf2f(bb[i][jc][0]); c[1] = bf2f(bb[i][jc][1]);
          c[2] = bf2f(bb[i][jc][2]); c[3] = bf2f(bb[i][jc][3]);
          s[i][jc] = __builtin_amdgcn_mfma_f32_16x16x32_bf16(qf[i][0], kf0[jc], c, 0, 0, 0);
        }
      #pragma unroll
      for (int i = 0; i < 2; ++i)
        #pragma unroll
        for (int jc = 0; jc < 4; ++jc)
          s[i][jc] = __builtin_amdgcn_mfma_f32_16x16x32_bf16(qf[i][1], kf1[jc], s[i][jc], 0, 0, 0);
      __builtin_amdgcn_s_setprio(0);

      if (t == tmaxw) {   // only the diagonal tile needs causal masking
        #pragma unroll
        for (int i = 0; i < 2; ++i)
          #pragma unroll
          for (int jc = 0; jc < 4; ++jc)
            #pragma unroll
            for (int r = 0; r < 4; ++r)
              if (j0 + jc*16 + fr > qoff + i*16 + fq*4 + r + 512)
                s[i][jc][r] = -1e30f;
      }

      #pragma unroll
      for (int i = 0; i < 2; ++i) {
        short* Pw = &Pb[wid][0];
        #pragma unroll
        for (int jc = 0; jc < 4; ++jc)
          #pragma unroll
          for (int r = 0; r < 4; ++r) {
            float p = exp2f(fminf(s[i][jc][r], 80.f));
            racc[i][r] += p;
            Pw[(fq*4 + r)*72 + jc*16 + fr] = f2bf(p);
          }
        asm volatile("s_waitcnt lgkmcnt(0)" ::: "memory");  // P visible cross-lane
        __builtin_amdgcn_sched_barrier(0);   // rule 18: pin reads after the wait
        __builtin_amdgcn_s_setprio(1);
        #pragma unroll
        for (int jk = 0; jk < 2; ++jk) {
          bf16x8 pf = *reinterpret_cast<const bf16x8*>(&Pw[fr*72 + jk*32 + fq*8]);
          #pragma unroll
          for (int dc = 0; dc < 4; ++dc)
            o[i][dc] = __builtin_amdgcn_mfma_f32_16x16x32_bf16(pf, vf[jk][dc], o[i][dc], 0, 0, 0);
        }
        __builtin_amdgcn_s_setprio(0);
        __builtin_amdgcn_sched_barrier(0);   // pin next-i P writes after these reads
      }
    }
    if (more) {   // write next K tile into the other buffer
      #pragma unroll
      for (int p = 0; p < 2; ++p)
        *reinterpret_cast<int4v*>(&Ks[buf ^ 1][soA + p*2304]) = kk[p];
    }
    __syncthreads();
  }

  // single end-of-kernel sum reduction across the 16 fr lanes
  #pragma unroll
  for (int i = 0; i < 2; ++i)
    #pragma unroll
    for (int off = 1; off < 16; off <<= 1)
      #pragma unroll
      for (int r = 0; r < 4; ++r)
        racc[i][r] += __shfl_xor(racc[i][r], off);

  short* obase = attnb + ((size_t)(b*SEQV + w*WIDTHV + qoff))*1024 + h*64;
  #pragma unroll
  for (int i = 0; i < 2; ++i) {
    float inv[4];
    #pragma unroll
    for (int r = 0; r < 4; ++r) inv[r] = 1.0f / racc[i][r];
    #pragma unroll
    for (int dc = 0; dc < 4; ++dc)
      #pragma unroll
      for (int r = 0; r < 4; ++r)
        obase[(size_t)(i*16 + fq*4 + r)*1024 + dc*16 + fr] = f2bf(o[i][dc][r] * inv[r]);
  }
}

// ------------------------------------------------------------------- host
extern "C" void kernel_launch(void* const* d_in, const int* in_sizes, int n_in,
                              void* d_out, int out_size, void* d_ws, size_t ws_size,
                              hipStream_t stream) {
  const float* x     = (const float*)d_in[0];
  const float* bias  = (const float*)d_in[1];
  const float* xl    = (const float*)d_in[2];
  const float* gamma = (const float*)d_in[3];
  const float* w_qkv = (const float*)d_in[4];
  const float* w_out = (const float*)d_in[5];
  float* out = (float*)d_out;
  float* mem_out = out + (size_t)BATCHV*SEQV*DIMV;   // +8388608

  char* ws = (char*)d_ws;
  size_t off = 0;
  auto alloc = [&](size_t bytes) { size_t o = off; off += (bytes + 255) & ~(size_t)255; return o; };
  short* xn    = (short*)(ws + alloc((size_t)NROWS*DIMV*2));          // aliased by attnb
  short* wqkvT = (short*)(ws + alloc((size_t)3*INNERV*DIMV*2));
  short* woutT = (short*)(ws + alloc((size_t)DIMV*INNERV*2));
  short* bp    = (short*)(ws + alloc((size_t)HEADSV*128*1024*4*2));   // packed bias
  short* qbuf  = (short*)(ws + alloc((size_t)NROWS*INNERV*2));
  short* k_all = (short*)(ws + alloc((size_t)BATCHV*HEADSV*KVROWS*DHEADV*2));
  short* vt    = (short*)(ws + alloc((size_t)BATCHV*HEADSV*KVROWS*DHEADV*2));
  short* attnb = xn;  // xn dead after QKV GEMM; reuse for attention output

  // weight transposes (fp32 (R,C) -> bf16 (C,R))
  transpose_f32_bf16<<<dim3(3*INNERV/32, DIMV/32), 256, 0, stream>>>(w_qkv, wqkvT, DIMV, 3*INNERV);
  transpose_f32_bf16<<<dim3(INNERV/32, DIMV/32), 256, 0, stream>>>(w_out, woutT, DIMV, INNERV);
  // bias -> fragment-packed bf16 (*log2e)
  pack_bias<<<8192, 256, 0, stream>>>(bias, bp);
  // xl memories -> k_all prefix (s-major) + vt prefix (d-major, transposed)
  xl_to_kv<<<2048, 256, 0, stream>>>(xl, k_all, vt);
  // layernorm
  ln_kernel<<<NROWS, 256, 0, stream>>>(x, gamma, xn);
  // QKV projection (q pre-scaled; K s-major; V -> vt via LDS-staged transpose;
  // memories fp32 epilogue) — transpose_v kernel deleted.
  gemm_bt<0><<<dim3(NROWS/128, (3*INNERV)/128), 256, 0, stream>>>(
      xn, wqkvT, qbuf, k_all, vt, mem_out, nullptr, 3*INNERV);
  // attention: 1024 blocks (heavy-first), 4 waves x 32 q-rows (R10 structure)
  attn_kernel<<<4*BATCHV*8*HEADSV, 256, 0, stream>>>(qbuf, k_all, vt, bp, attnb);
  // output projection -> fp32 d_out
  gemm_bt<1><<<dim3(NROWS/128, INNERV/128), 256, 0, stream>>>(
      attnb, woutT, nullptr, nullptr, nullptr, nullptr, out, INNERV);
}